// Round 2
// baseline (529.306 us; speedup 1.0000x reference)
//
#include <hip/hip_runtime.h>
#include <cmath>

#define IGNORE_INDEX (-100)
#define SMOOTHING 0.2f

__device__ __forceinline__ float wave_reduce_max(float v) {
#pragma unroll
    for (int off = 32; off > 0; off >>= 1)
        v = fmaxf(v, __shfl_xor(v, off, 64));
    return v;
}
__device__ __forceinline__ float wave_reduce_sum(float v) {
#pragma unroll
    for (int off = 32; off > 0; off >>= 1)
        v += __shfl_xor(v, off, 64);
    return v;
}

// Kernel A: per-class soft row S[c][j] = 0.8*d(j==c) + 0.2*sim[c][j]/rowsum,
// and per-class entropy H[c] = sum_j S*log(S) (0log0 := 0). One wave per class.
__global__ void prep_kernel(const float* __restrict__ sim, float* __restrict__ S,
                            float* __restrict__ H, float* __restrict__ acc, int C) {
    const int c = blockIdx.x;
    const int lane = threadIdx.x;  // blockDim.x == 64
    if (c == 0 && lane == 0) acc[0] = 0.f;  // zeroed before main_kernel dispatch (same stream)

    float psum = 0.f;
    for (int j = lane; j < C; j += 64) psum += sim[(size_t)c * C + j];
    const float inv = 1.f / wave_reduce_sum(psum);

    float h = 0.f;
    for (int j = lane; j < C; j += 64) {
        float s = SMOOTHING * sim[(size_t)c * C + j] * inv + ((j == c) ? (1.f - SMOOTHING) : 0.f);
        S[(size_t)c * C + j] = s;
        if (s > 0.f) h += s * logf(s);
    }
    h = wave_reduce_sum(h);
    if (lane == 0) H[c] = h;
}

// Kernel B: one wave per sample (grid-stride). kl_i = H[t] - dot(S[t], x_i) + lse_i.
// Rows are C=170 floats = 680 B, 8B-aligned -> float2 loads (512 B/wave/instr).
__global__ __launch_bounds__(256) void main_kernel(
    const float* __restrict__ logits, const int* __restrict__ targets,
    const float* __restrict__ S, const float* __restrict__ H,
    float* __restrict__ acc, int Bn, int C) {
    const int lane = threadIdx.x & 63;
    const int wid = threadIdx.x >> 6;
    const int wave = blockIdx.x * 4 + wid;
    const int nwaves = gridDim.x * 4;
    const int n2 = C >> 1;                 // float2 per row (C even)
    const bool has2 = (lane + 64) < n2;    // second-chunk lanes (lane < 21 for C=170)

    float wsum = 0.f;
    for (int i = wave; i < Bn; i += nwaves) {
        const int t = targets[i];          // wave-uniform
        if (t == IGNORE_INDEX) continue;

        const float2* xr = (const float2*)(logits + (size_t)i * C);
        const float2* sr = (const float2*)(S + (size_t)t * C);
        float2 xa = xr[lane];
        float2 sa = sr[lane];
        float2 xb = make_float2(-INFINITY, -INFINITY);
        float2 sb = make_float2(0.f, 0.f);
        if (has2) { xb = xr[lane + 64]; sb = sr[lane + 64]; }

        float m = fmaxf(fmaxf(xa.x, xa.y), fmaxf(xb.x, xb.y));
        m = wave_reduce_max(m);

        float se = __expf(xa.x - m) + __expf(xa.y - m);
        float dot = sa.x * xa.x + sa.y * xa.y;
        if (has2) {
            se += __expf(xb.x - m) + __expf(xb.y - m);
            dot += sb.x * xb.x + sb.y * xb.y;
        }
        se = wave_reduce_sum(se);
        dot = wave_reduce_sum(dot);

        const float lse = m + __logf(se);
        wsum += H[t] - dot + lse;
    }

    __shared__ float wsums[4];
    if (lane == 0) wsums[wid] = wsum;
    __syncthreads();
    if (threadIdx.x == 0)
        atomicAdd(acc, wsums[0] + wsums[1] + wsums[2] + wsums[3]);
}

// Kernel C: loss = max(acc / B, 0)
__global__ void finish_kernel(const float* __restrict__ acc, float* __restrict__ out,
                              float invB) {
    if (threadIdx.x == 0 && blockIdx.x == 0)
        out[0] = fmaxf(acc[0] * invB, 0.f);
}

extern "C" void kernel_launch(void* const* d_in, const int* in_sizes, int n_in,
                              void* d_out, int out_size, void* d_ws, size_t ws_size,
                              hipStream_t stream) {
    const float* logits = (const float*)d_in[0];
    const int* targets = (const int*)d_in[1];
    const float* sim = (const float*)d_in[2];
    float* out = (float*)d_out;

    const int Bn = in_sizes[1];
    const int C = in_sizes[0] / Bn;

    char* ws = (char*)d_ws;
    float* S = (float*)ws;                                   // C*C floats
    float* H = (float*)(ws + (size_t)C * C * sizeof(float)); // C floats
    size_t off = ((size_t)C * C + (size_t)C) * sizeof(float);
    off = (off + 255) & ~(size_t)255;
    float* acc = (float*)(ws + off);                         // 1 float accumulator

    prep_kernel<<<C, 64, 0, stream>>>(sim, S, H, acc, C);

    // 2048 blocks x 4 waves = 8192 waves -> fills 256 CUs at 32 waves/CU; each
    // wave handles Bn/8192 = 64 samples.
    main_kernel<<<2048, 256, 0, stream>>>(logits, targets, S, H, acc, Bn, C);

    finish_kernel<<<1, 64, 0, stream>>>(acc, out, 1.0f / (float)Bn);
}

// Round 3
// 525.818 us; speedup vs baseline: 1.0066x; 1.0066x over previous
//
#include <hip/hip_runtime.h>
#include <cmath>

#define IGNORE_INDEX (-100)
#define SMOOTHING 0.2f

__device__ __forceinline__ float wave_reduce_max(float v) {
#pragma unroll
    for (int off = 32; off > 0; off >>= 1)
        v = fmaxf(v, __shfl_xor(v, off, 64));
    return v;
}
__device__ __forceinline__ float wave_reduce_sum(float v) {
#pragma unroll
    for (int off = 32; off > 0; off >>= 1)
        v += __shfl_xor(v, off, 64);
    return v;
}

// Kernel A: per-class soft row S[c][j] = 0.8*d(j==c) + 0.2*sim[c][j]/rowsum,
// and per-class entropy H[c] = sum_j S*log(S). One wave per class.
__global__ void prep_kernel(const float* __restrict__ sim, float* __restrict__ S,
                            float* __restrict__ H, float* __restrict__ acc, int C) {
    const int c = blockIdx.x;
    const int lane = threadIdx.x;  // blockDim.x == 64
    if (c == 0 && lane == 0) acc[0] = 0.f;  // consumed by main_kernel (stream-ordered)

    float psum = 0.f;
    for (int j = lane; j < C; j += 64) psum += sim[(size_t)c * C + j];
    const float inv = 1.f / wave_reduce_sum(psum);

    float h = 0.f;
    for (int j = lane; j < C; j += 64) {
        float s = SMOOTHING * sim[(size_t)c * C + j] * inv + ((j == c) ? (1.f - SMOOTHING) : 0.f);
        S[(size_t)c * C + j] = s;
        if (s > 0.f) h += s * logf(s);
    }
    h = wave_reduce_sum(h);
    if (lane == 0) H[c] = h;
}

// Kernel B: one wave per CONTIGUOUS span of samples (DRAM-sequential streams).
// kl_i = H[t] - dot(S[t], x_i) + lse_i. dot is linear in the final sum ->
// accumulate per-lane partials, reduce ONCE per wave (saves 6 shuffles/sample).
// 2-sample unroll + branchless validity so two load/reduce chains overlap.
__global__ __launch_bounds__(256) void main_kernel(
    const float* __restrict__ logits, const int* __restrict__ targets,
    const float* __restrict__ S, const float* __restrict__ H,
    float* __restrict__ acc, int Bn, int C) {
    const int lane = threadIdx.x & 63;
    const int wid = threadIdx.x >> 6;
    const int wave = blockIdx.x * 4 + wid;
    const int nwaves = gridDim.x * 4;
    const int spw = (Bn + nwaves - 1) / nwaves;     // samples per wave (64)
    const int start = wave * spw;
    const int end = (start + spw < Bn) ? (start + spw) : Bn;

    const int n2 = C >> 1;                 // float2 per row (C even)
    const bool has2 = (lane + 64) < n2;    // lanes covering elements 128..169

    float dotacc = 0.f;   // per-lane, reduced once at the end
    float usum = 0.f;     // wave-uniform sum of valid*(H[t] + lse)

    int i = start;
    for (; i + 1 < end; i += 2) {
        const int t0 = targets[i];
        const int t1 = targets[i + 1];
        const bool v0 = (t0 != IGNORE_INDEX);
        const bool v1 = (t1 != IGNORE_INDEX);
        const int i0 = v0 ? t0 : 0;
        const int i1 = v1 ? t1 : 0;

        const float2* xr0 = (const float2*)(logits + (size_t)i * C);
        const float2* xr1 = (const float2*)(logits + (size_t)(i + 1) * C);
        const float2* sr0 = (const float2*)(S + (size_t)i0 * C);
        const float2* sr1 = (const float2*)(S + (size_t)i1 * C);

        float2 x0a = xr0[lane];
        float2 x1a = xr1[lane];
        float2 s0a = sr0[lane];
        float2 s1a = sr1[lane];
        float2 x0b = make_float2(-INFINITY, -INFINITY);
        float2 x1b = make_float2(-INFINITY, -INFINITY);
        float2 s0b = make_float2(0.f, 0.f);
        float2 s1b = make_float2(0.f, 0.f);
        if (has2) {
            x0b = xr0[lane + 64]; s0b = sr0[lane + 64];
            x1b = xr1[lane + 64]; s1b = sr1[lane + 64];
        }

        // interleaved max reductions (two independent chains)
        float m0 = fmaxf(fmaxf(x0a.x, x0a.y), fmaxf(x0b.x, x0b.y));
        float m1 = fmaxf(fmaxf(x1a.x, x1a.y), fmaxf(x1b.x, x1b.y));
#pragma unroll
        for (int off = 32; off > 0; off >>= 1) {
            m0 = fmaxf(m0, __shfl_xor(m0, off, 64));
            m1 = fmaxf(m1, __shfl_xor(m1, off, 64));
        }

        float se0 = __expf(x0a.x - m0) + __expf(x0a.y - m0);
        float se1 = __expf(x1a.x - m1) + __expf(x1a.y - m1);
        if (has2) {
            se0 += __expf(x0b.x - m0) + __expf(x0b.y - m0);
            se1 += __expf(x1b.x - m1) + __expf(x1b.y - m1);
        }
#pragma unroll
        for (int off = 32; off > 0; off >>= 1) {
            se0 += __shfl_xor(se0, off, 64);
            se1 += __shfl_xor(se1, off, 64);
        }

        float d0 = s0a.x * x0a.x + s0a.y * x0a.y;
        float d1 = s1a.x * x1a.x + s1a.y * x1a.y;
        if (has2) {
            d0 += s0b.x * x0b.x + s0b.y * x0b.y;
            d1 += s1b.x * x1b.x + s1b.y * x1b.y;
        }
        dotacc += (v0 ? d0 : 0.f) + (v1 ? d1 : 0.f);

        usum += (v0 ? (H[i0] + m0 + __logf(se0)) : 0.f)
              + (v1 ? (H[i1] + m1 + __logf(se1)) : 0.f);
    }
    // tail (at most one sample)
    for (; i < end; ++i) {
        const int t0 = targets[i];
        const bool v0 = (t0 != IGNORE_INDEX);
        const int i0 = v0 ? t0 : 0;
        const float2* xr0 = (const float2*)(logits + (size_t)i * C);
        const float2* sr0 = (const float2*)(S + (size_t)i0 * C);
        float2 x0a = xr0[lane];
        float2 s0a = sr0[lane];
        float2 x0b = make_float2(-INFINITY, -INFINITY);
        float2 s0b = make_float2(0.f, 0.f);
        if (has2) { x0b = xr0[lane + 64]; s0b = sr0[lane + 64]; }
        float m0 = fmaxf(fmaxf(x0a.x, x0a.y), fmaxf(x0b.x, x0b.y));
        m0 = wave_reduce_max(m0);
        float se0 = __expf(x0a.x - m0) + __expf(x0a.y - m0);
        float d0 = s0a.x * x0a.x + s0a.y * x0a.y;
        if (has2) {
            se0 += __expf(x0b.x - m0) + __expf(x0b.y - m0);
            d0 += s0b.x * x0b.x + s0b.y * x0b.y;
        }
        se0 = wave_reduce_sum(se0);
        dotacc += v0 ? d0 : 0.f;
        usum += v0 ? (H[i0] + m0 + __logf(se0)) : 0.f;
    }

    const float wsum = usum - wave_reduce_sum(dotacc);  // wave-uniform

    __shared__ float wsums[4];
    if (lane == 0) wsums[wid] = wsum;
    __syncthreads();
    if (threadIdx.x == 0)
        atomicAdd(acc, wsums[0] + wsums[1] + wsums[2] + wsums[3]);
}

// Kernel C: loss = max(acc / B, 0)
__global__ void finish_kernel(const float* __restrict__ acc, float* __restrict__ out,
                              float invB) {
    if (threadIdx.x == 0 && blockIdx.x == 0)
        out[0] = fmaxf(acc[0] * invB, 0.f);
}

extern "C" void kernel_launch(void* const* d_in, const int* in_sizes, int n_in,
                              void* d_out, int out_size, void* d_ws, size_t ws_size,
                              hipStream_t stream) {
    const float* logits = (const float*)d_in[0];
    const int* targets = (const int*)d_in[1];
    const float* sim = (const float*)d_in[2];
    float* out = (float*)d_out;

    const int Bn = in_sizes[1];
    const int C = in_sizes[0] / Bn;

    char* ws = (char*)d_ws;
    float* S = (float*)ws;                                   // C*C floats
    float* H = (float*)(ws + (size_t)C * C * sizeof(float)); // C floats
    size_t off = ((size_t)C * C + (size_t)C) * sizeof(float);
    off = (off + 255) & ~(size_t)255;
    float* acc = (float*)(ws + off);                         // 1 float accumulator

    prep_kernel<<<C, 64, 0, stream>>>(sim, S, H, acc, C);

    // 2048 blocks x 4 waves = 8192 waves; each wave owns a CONTIGUOUS 64-sample
    // span (43.5 KB sequential stream) for DRAM page locality.
    main_kernel<<<2048, 256, 0, stream>>>(logits, targets, S, H, acc, Bn, C);

    finish_kernel<<<1, 64, 0, stream>>>(acc, out, 1.0f / (float)Bn);
}

// Round 4
// 494.492 us; speedup vs baseline: 1.0704x; 1.0633x over previous
//
#include <hip/hip_runtime.h>
#include <cmath>

#define IGNORE_INDEX (-100)
#define SMOOTHING 0.2f

__device__ __forceinline__ float wave_reduce_max(float v) {
#pragma unroll
    for (int off = 32; off > 0; off >>= 1)
        v = fmaxf(v, __shfl_xor(v, off, 64));
    return v;
}
__device__ __forceinline__ float wave_reduce_sum(float v) {
#pragma unroll
    for (int off = 32; off > 0; off >>= 1)
        v += __shfl_xor(v, off, 64);
    return v;
}

// Kernel A: per-class soft row S[c][j] = 0.8*d(j==c) + 0.2*sim[c][j]/rowsum,
// and per-class entropy H[c] = sum_j S*log(S). One wave per class.
__global__ void prep_kernel(const float* __restrict__ sim, float* __restrict__ S,
                            float* __restrict__ H, float* __restrict__ acc, int C) {
    const int c = blockIdx.x;
    const int lane = threadIdx.x;  // blockDim.x == 64
    if (c == 0 && lane == 0) acc[0] = 0.f;  // consumed by main kernel (stream-ordered)

    float psum = 0.f;
    for (int j = lane; j < C; j += 64) psum += sim[(size_t)c * C + j];
    const float inv = 1.f / wave_reduce_sum(psum);

    float h = 0.f;
    for (int j = lane; j < C; j += 64) {
        float s = SMOOTHING * sim[(size_t)c * C + j] * inv + ((j == c) ? (1.f - SMOOTHING) : 0.f);
        S[(size_t)c * C + j] = s;
        if (s > 0.f) h += s * logf(s);
    }
    h = wave_reduce_sum(h);
    if (lane == 0) H[c] = h;
}

// Kernel B (C known at compile time): 16 LANES PER SAMPLE.
// The LDS/DS pipe is CU-shared (4 SIMDs -> one LDS unit), so shuffle chains
// dominate: v2 spent 12 DS ops/sample = ~60us/CU on the LDS pipe alone.
// Here lanes split into 4 groups of 16; xor-shuffle offsets 8,4,2,1 reduce
// all FOUR samples in one 4-step chain -> 2 DS ops/sample (6x fewer).
// kl_i = H[t] - dot(S[t],x_i) + lse_i; dot accumulates per-lane, reduced once.
template <int CC>
__global__ __launch_bounds__(256) void main_kernel_t(
    const float* __restrict__ logits, const int* __restrict__ targets,
    const float* __restrict__ S, const float* __restrict__ H,
    float* __restrict__ acc, int Bn) {
    constexpr int NF2 = CC / 2;              // float2 per row (85)
    constexpr int NCH = (NF2 + 15) / 16;     // chunks per 16-lane group (6)

    const int lane = threadIdx.x & 63;
    const int wid  = threadIdx.x >> 6;
    const int wave = blockIdx.x * 4 + wid;
    const int nwaves = gridDim.x * 4;
    const int spw = (Bn + nwaves - 1) / nwaves;     // samples per wave (64)
    const int start = wave * spw;
    const int end = (start + spw < Bn) ? (start + spw) : Bn;

    const int g = lane >> 4;    // which of 4 samples this lane serves
    const int u = lane & 15;    // sublane within the 16-lane group

    float dotacc = 0.f;   // per-lane, folded into the single final reduction
    float usum   = 0.f;   // per-lane, only u==0 lanes contribute

    for (int i = start; i < end; i += 4) {
        const int s_idx = i + g;
        const bool in_range = (s_idx < end);
        const int t = in_range ? targets[s_idx] : IGNORE_INDEX;
        const bool v = in_range && (t != IGNORE_INDEX);
        const int cls = v ? t : 0;

        const float2* xr = (const float2*)(logits + (size_t)(in_range ? s_idx : start) * CC);
        const float2* sr = (const float2*)(S + (size_t)cls * CC);

        float2 x[NCH], sv[NCH];
#pragma unroll
        for (int c = 0; c < NCH; ++c) {
            const bool ok = (c * 16 + u < NF2) && in_range;
            x[c]  = ok ? xr[c * 16 + u] : make_float2(-INFINITY, -INFINITY);
            sv[c] = ok ? sr[c * 16 + u] : make_float2(0.f, 0.f);
        }

        // group max: 4-step chain serves all 4 samples at once
        float m = -INFINITY;
#pragma unroll
        for (int c = 0; c < NCH; ++c) m = fmaxf(m, fmaxf(x[c].x, x[c].y));
#pragma unroll
        for (int off = 8; off >= 1; off >>= 1)
            m = fmaxf(m, __shfl_xor(m, off, 64));

        float se = 0.f, d = 0.f;
#pragma unroll
        for (int c = 0; c < NCH; ++c) {
            se += __expf(x[c].x - m) + __expf(x[c].y - m);
            // guard: sentinel slots have sv=0 but x=-INF -> 0*inf = NaN
            const bool ok = (c * 16 + u < NF2) && in_range;
            d += ok ? (sv[c].x * x[c].x + sv[c].y * x[c].y) : 0.f;
        }
#pragma unroll
        for (int off = 8; off >= 1; off >>= 1)
            se += __shfl_xor(se, off, 64);

        dotacc += v ? d : 0.f;
        const float lse = m + __logf(se);
        usum += (v && u == 0) ? (H[cls] + lse) : 0.f;
    }

    float tot = usum - dotacc;
    tot = wave_reduce_sum(tot);   // once per wave, amortized over 64 samples

    __shared__ float wsums[4];
    if (lane == 0) wsums[wid] = tot;
    __syncthreads();
    if (threadIdx.x == 0)
        atomicAdd(acc, wsums[0] + wsums[1] + wsums[2] + wsums[3]);
}

// Generic fallback (C != 170): one wave per sample, grid-stride.
__global__ __launch_bounds__(256) void main_kernel_gen(
    const float* __restrict__ logits, const int* __restrict__ targets,
    const float* __restrict__ S, const float* __restrict__ H,
    float* __restrict__ acc, int Bn, int C) {
    const int lane = threadIdx.x & 63;
    const int wid = threadIdx.x >> 6;
    const int wave = blockIdx.x * 4 + wid;
    const int nwaves = gridDim.x * 4;

    float wsum = 0.f;
    for (int i = wave; i < Bn; i += nwaves) {
        const int t = targets[i];
        const bool v = (t != IGNORE_INDEX);
        const int cls = v ? t : 0;
        const float* xr = logits + (size_t)i * C;
        const float* sr = S + (size_t)cls * C;
        float m = -INFINITY;
        for (int j = lane; j < C; j += 64) m = fmaxf(m, xr[j]);
        m = wave_reduce_max(m);
        float se = 0.f, d = 0.f;
        for (int j = lane; j < C; j += 64) {
            se += __expf(xr[j] - m);
            d += sr[j] * xr[j];
        }
        se = wave_reduce_sum(se);
        d = wave_reduce_sum(d);
        wsum += v ? (H[cls] + m + __logf(se) - d) : 0.f;
    }
    __shared__ float wsums[4];
    if (lane == 0) wsums[wid] = wsum;
    __syncthreads();
    if (threadIdx.x == 0)
        atomicAdd(acc, wsums[0] + wsums[1] + wsums[2] + wsums[3]);
}

// Kernel C: loss = max(acc / B, 0)
__global__ void finish_kernel(const float* __restrict__ acc, float* __restrict__ out,
                              float invB) {
    if (threadIdx.x == 0 && blockIdx.x == 0)
        out[0] = fmaxf(acc[0] * invB, 0.f);
}

extern "C" void kernel_launch(void* const* d_in, const int* in_sizes, int n_in,
                              void* d_out, int out_size, void* d_ws, size_t ws_size,
                              hipStream_t stream) {
    const float* logits = (const float*)d_in[0];
    const int* targets = (const int*)d_in[1];
    const float* sim = (const float*)d_in[2];
    float* out = (float*)d_out;

    const int Bn = in_sizes[1];
    const int C = in_sizes[0] / Bn;

    char* ws = (char*)d_ws;
    float* S = (float*)ws;                                   // C*C floats
    float* H = (float*)(ws + (size_t)C * C * sizeof(float)); // C floats
    size_t off = ((size_t)C * C + (size_t)C) * sizeof(float);
    off = (off + 255) & ~(size_t)255;
    float* acc = (float*)(ws + off);                         // 1 float accumulator

    prep_kernel<<<C, 64, 0, stream>>>(sim, S, H, acc, C);

    // 2048 blocks x 4 waves = 8192 waves; each wave owns a contiguous
    // 64-sample span, processed 4 samples per iteration (16 lanes each).
    if (C == 170) {
        main_kernel_t<170><<<2048, 256, 0, stream>>>(logits, targets, S, H, acc, Bn);
    } else {
        main_kernel_gen<<<2048, 256, 0, stream>>>(logits, targets, S, H, acc, Bn, C);
    }

    finish_kernel<<<1, 64, 0, stream>>>(acc, out, 1.0f / (float)Bn);
}